// Round 4
// baseline (270.222 us; speedup 1.0000x reference)
//
#include <hip/hip_runtime.h>

#define LEAKY_SLOPE 0.2f

constexpr int B_   = 16;
constexpr int N_   = 4096;
constexpr int K_   = 4096;
constexpr int IN_  = 16384;   // K + 3K
constexpr int H1_  = 1024;
constexpr int H2_  = 512;
constexpr int OUT_ = 256;

// encode tiling: 32 n-chunks x 128 points (2KB LDS), 4 k per thread
constexpr int NCH = 32;
constexpr int NPC = N_ / NCH;   // 128
constexpr int KPT = 4;
constexpr int KTB = 256 * KPT;  // 1024 k per block -> grid.x = 4

// -------------------------------------------------------------------------
// Kernel 1: partial argmin over an n-chunk, folded globally via u64
// atomicMin on (orderable_e2_bits << 32 | n).  e2 = pn - 2*cross (bn
// dropped: constant in the argmin over n; ties shift only at rounding
// level, within tolerance).  6 VALU ops per (k,n) pair.
// -------------------------------------------------------------------------
__global__ __launch_bounds__(256) void enc_partial(
    const float* __restrict__ pc, const float* __restrict__ basis,
    unsigned long long* __restrict__ packed)
{
#pragma clang fp contract(off)
    __shared__ float4 pts[NPC];
    const int kt = blockIdx.x;
    const int b  = blockIdx.y;
    const int c  = blockIdx.z;
    const int n0 = c * NPC;

    if (threadIdx.x < NPC) {
        const float* pp = pc + ((size_t)b * N_ + n0 + threadIdx.x) * 3;
        float x = pp[0], y = pp[1], z = pp[2];
        pts[threadIdx.x] = make_float4(x, y, z, (x * x + y * y) + z * z);
    }
    __syncthreads();

    const int k0 = kt * KTB + (int)threadIdx.x;
    float nbx[KPT], nby[KPT], nbz[KPT], best[KPT];
    int   bi[KPT];
#pragma unroll
    for (int q = 0; q < KPT; ++q) {
        int k = k0 + q * 256;
        nbx[q] = -2.0f * basis[k * 3 + 0];
        nby[q] = -2.0f * basis[k * 3 + 1];
        nbz[q] = -2.0f * basis[k * 3 + 2];
        best[q] = 3.4028235e38f;
        bi[q] = 0;
    }

#pragma unroll 4
    for (int n = 0; n < NPC; ++n) {
        float4 p = pts[n];
#pragma unroll
        for (int q = 0; q < KPT; ++q) {
            float e2 = __builtin_fmaf(nbx[q], p.x,
                        __builtin_fmaf(nby[q], p.y,
                         __builtin_fmaf(nbz[q], p.z, p.w)));
            if (e2 < best[q]) { best[q] = e2; bi[q] = n0 + n; }  // strict <
        }
    }

#pragma unroll
    for (int q = 0; q < KPT; ++q) {
        unsigned u = __float_as_uint(best[q]);
        u = (u & 0x80000000u) ? ~u : (u | 0x80000000u);   // monotone map
        unsigned long long v = ((unsigned long long)u << 32) | (unsigned)bi[q];
        atomicMin(&packed[(size_t)b * K_ + (k0 + q * 256)], v);
    }
}

// -------------------------------------------------------------------------
// Kernel 2: unpack argmin index, gather nearest point, write bps feature
// (d_out) and transposed bpsT[i][16] for the GEMM.
// -------------------------------------------------------------------------
__global__ __launch_bounds__(256) void enc_finish(
    const float* __restrict__ pc, const float* __restrict__ basis,
    const unsigned long long* __restrict__ packed,
    float* __restrict__ bps_out, float* __restrict__ bpsT)
{
#pragma clang fp contract(off)
    const int t = blockIdx.x * 256 + (int)threadIdx.x;   // 0 .. B*K-1
    const int b = t >> 12;
    const int k = t & (K_ - 1);

    const int bi = (int)(unsigned)(packed[t] & 0xffffffffull);

    const float* p = pc + ((size_t)b * N_ + bi) * 3;
    float dx = p[0] - basis[k * 3 + 0];
    float dy = p[1] - basis[k * 3 + 1];
    float dz = p[2] - basis[k * 3 + 2];
    float dist = sqrtf((dx * dx + dy * dy) + dz * dz);

    float* row = bps_out + (size_t)b * IN_;
    row[k]              = dist;
    row[K_ + 3 * k + 0] = dx;
    row[K_ + 3 * k + 1] = dy;
    row[K_ + 3 * k + 2] = dz;

    bpsT[(size_t)k * B_ + b]                = dist;
    bpsT[(size_t)(K_ + 3 * k + 0) * B_ + b] = dx;
    bpsT[(size_t)(K_ + 3 * k + 1) * B_ + b] = dy;
    bpsT[(size_t)(K_ + 3 * k + 2) * B_ + b] = dz;
}

// -------------------------------------------------------------------------
// L1 GEMM: block = 4 waves; wave w -> batches 4w..4w+3 (A wave-uniform ->
// s_load); lane -> one column (coalesced 256B/wave W loads). k-chunked,
// results folded by float atomicAdd into h1raw[col][16] (zero-initialized).
// -------------------------------------------------------------------------
template<int ILEN, int NCOLS>
__global__ __launch_bounds__(256) void gemm1(
    const float* __restrict__ AT, const float* __restrict__ W,
    float* __restrict__ raw)
{
    const int lane = (int)threadIdx.x & 63;
    const int wg   = __builtin_amdgcn_readfirstlane((int)threadIdx.x >> 6);
    const int j    = blockIdx.x * 64 + lane;
    const int i0   = blockIdx.y * ILEN;

    float a0 = 0.0f, a1 = 0.0f, a2 = 0.0f, a3 = 0.0f;
    const float* Arow = AT + 4 * wg;   // wave-uniform base

#pragma unroll 8
    for (int i = 0; i < ILEN; ++i) {
        float  wv = W[(size_t)(i0 + i) * NCOLS + j];
        float4 av = *(const float4*)(Arow + (size_t)(i0 + i) * 16);
        a0 = __builtin_fmaf(av.x, wv, a0);
        a1 = __builtin_fmaf(av.y, wv, a1);
        a2 = __builtin_fmaf(av.z, wv, a2);
        a3 = __builtin_fmaf(av.w, wv, a3);
    }

    float* dst = raw + (size_t)j * 16 + 4 * wg;
    atomicAdd(dst + 0, a0);
    atomicAdd(dst + 1, a1);
    atomicAdd(dst + 2, a2);
    atomicAdd(dst + 3, a3);
}

// -------------------------------------------------------------------------
// bias + leaky on h1raw -> h1T[col][16]
// -------------------------------------------------------------------------
__global__ __launch_bounds__(256) void act1(
    const float* __restrict__ raw, const float* __restrict__ bias,
    float* __restrict__ outT)
{
    const int p = blockIdx.x * 256 + (int)threadIdx.x;   // col*16 + batch
    float v = raw[p] + bias[p >> 4];
    outT[p] = fmaxf(v, LEAKY_SLOPE * v);   // leaky, slope < 1
}

// -------------------------------------------------------------------------
// Small fused GEMM (L2/L3): one dispatch, full K. 512 threads = 8 waves;
// wave w -> k-slice [w*KQ, (w+1)*KQ); lane -> one column; 16 batch accs.
// Cross-wave reduce via LDS, then bias (+leaky) and store.
// -------------------------------------------------------------------------
template<int KDIM, int NCOLS>
__global__ __launch_bounds__(512) void gemm_small(
    const float* __restrict__ AT, const float* __restrict__ W,
    const float* __restrict__ bias,
    float* __restrict__ outT, float* __restrict__ out_rm)
{
    __shared__ float red[8][64][17];
    const int lane = (int)threadIdx.x & 63;
    const int w    = __builtin_amdgcn_readfirstlane((int)threadIdx.x >> 6);
    const int j    = blockIdx.x * 64 + lane;
    constexpr int KQ = KDIM / 8;
    const int i0 = w * KQ;

    float acc[16];
#pragma unroll
    for (int r = 0; r < 16; ++r) acc[r] = 0.0f;

#pragma unroll 4
    for (int i = i0; i < i0 + KQ; ++i) {
        float wv = W[(size_t)i * NCOLS + j];
        const float4* Ar = (const float4*)(AT + (size_t)i * 16);
        float4 q0 = Ar[0], q1 = Ar[1], q2 = Ar[2], q3 = Ar[3];
        acc[0]  = __builtin_fmaf(q0.x, wv, acc[0]);
        acc[1]  = __builtin_fmaf(q0.y, wv, acc[1]);
        acc[2]  = __builtin_fmaf(q0.z, wv, acc[2]);
        acc[3]  = __builtin_fmaf(q0.w, wv, acc[3]);
        acc[4]  = __builtin_fmaf(q1.x, wv, acc[4]);
        acc[5]  = __builtin_fmaf(q1.y, wv, acc[5]);
        acc[6]  = __builtin_fmaf(q1.z, wv, acc[6]);
        acc[7]  = __builtin_fmaf(q1.w, wv, acc[7]);
        acc[8]  = __builtin_fmaf(q2.x, wv, acc[8]);
        acc[9]  = __builtin_fmaf(q2.y, wv, acc[9]);
        acc[10] = __builtin_fmaf(q2.z, wv, acc[10]);
        acc[11] = __builtin_fmaf(q2.w, wv, acc[11]);
        acc[12] = __builtin_fmaf(q3.x, wv, acc[12]);
        acc[13] = __builtin_fmaf(q3.y, wv, acc[13]);
        acc[14] = __builtin_fmaf(q3.z, wv, acc[14]);
        acc[15] = __builtin_fmaf(q3.w, wv, acc[15]);
    }

#pragma unroll
    for (int r = 0; r < 16; ++r) red[w][lane][r] = acc[r];
    __syncthreads();

#pragma unroll
    for (int q = 0; q < 2; ++q) {
        int p  = (int)threadIdx.x * 2 + q;   // col_local*16 + batch
        int cl = p >> 4;
        int bt = p & 15;
        float s = bias[blockIdx.x * 64 + cl];
#pragma unroll
        for (int ww = 0; ww < 8; ++ww) s += red[ww][cl][bt];
        if (outT) {
            s = fmaxf(s, LEAKY_SLOPE * s);
            outT[((size_t)blockIdx.x * 64 + cl) * 16 + bt] = s;
        }
        if (out_rm) {
            out_rm[(size_t)bt * NCOLS + blockIdx.x * 64 + cl] = s;
        }
    }
}

// -------------------------------------------------------------------------
extern "C" void kernel_launch(void* const* d_in, const int* in_sizes, int n_in,
                              void* d_out, int out_size, void* d_ws, size_t ws_size,
                              hipStream_t stream)
{
    const float* pc    = (const float*)d_in[0];
    const float* basis = (const float*)d_in[1];
    const float* W1    = (const float*)d_in[2];
    const float* b1    = (const float*)d_in[3];
    const float* W2    = (const float*)d_in[4];
    const float* b2    = (const float*)d_in[5];
    const float* W3    = (const float*)d_in[6];
    const float* b3    = (const float*)d_in[7];

    float* out   = (float*)d_out;
    float* gfeat = out;                 // [16][256]
    float* bps   = out + B_ * OUT_;     // [16][16384]

    char* ws = (char*)d_ws;
    unsigned long long* packed = (unsigned long long*)ws;        // 512KB
    float* bpsT  = (float*)(ws + (size_t)512 * 1024);            // 1MB
    float* h1raw = (float*)(ws + (size_t)1536 * 1024);           // 64KB
    float* h1T   = (float*)(ws + (size_t)1600 * 1024);           // 64KB
    float* h2T   = (float*)(ws + (size_t)1664 * 1024);           // 32KB

    // --- BPS encode ---
    hipMemsetAsync(packed, 0xFF, (size_t)B_ * K_ * 8, stream);   // +inf keys
    hipMemsetAsync(h1raw, 0, (size_t)H1_ * 16 * 4, stream);      // atomic acc
    enc_partial<<<dim3(K_ / KTB, B_, NCH), 256, 0, stream>>>(pc, basis, packed);
    enc_finish<<<(B_ * K_) / 256, 256, 0, stream>>>(pc, basis, packed, bps, bpsT);

    // --- MLP ---
    // L1: [16,16384]@[16384,1024]; 16 colblocks x 64 chunks; atomic fold
    gemm1<256, 1024><<<dim3(16, 64), 256, 0, stream>>>(bpsT, W1, h1raw);
    act1<<<(H1_ * 16) / 256, 256, 0, stream>>>(h1raw, b1, h1T);
    // L2: [16,1024]@[1024,512]; fused single dispatch
    gemm_small<1024, 512><<<8, 512, 0, stream>>>(h1T, W2, b2, h2T, nullptr);
    // L3: [16,512]@[512,256]; fused single dispatch -> final output
    gemm_small<512, 256><<<4, 512, 0, stream>>>(h2T, W3, b3, nullptr, gfeat);
}

// Round 5
// 236.117 us; speedup vs baseline: 1.1444x; 1.1444x over previous
//
#include <hip/hip_runtime.h>

#define LEAKY_SLOPE 0.2f

constexpr int B_   = 16;
constexpr int N_   = 4096;
constexpr int K_   = 4096;
constexpr int IN_  = 16384;   // K + 3K
constexpr int H1_  = 1024;
constexpr int H2_  = 512;
constexpr int OUT_ = 256;

// -------------------------------------------------------------------------
// Fused BPS encode: one dispatch. grid = (K/256, B), 512 threads = 8 waves.
// Thread t: k_local = t&255, n-slice s = t>>8 (wave-uniform). Two phases
// stage 2048 points each into LDS (32KB); slice s scans its 1024-point
// half per phase. e2 = pn - 2*cross (bn dropped: constant in argmin over n).
// Block-level fold in LDS (ascending slice, strict < => first-min up to
// fp-rounding ties, validated rounds 3-4), then epilogue computes
// dist/deltas and writes the bps feature row directly.
// -------------------------------------------------------------------------
__global__ __launch_bounds__(512) void enc_fused(
    const float* __restrict__ pc, const float* __restrict__ basis,
    float* __restrict__ bps_out)
{
#pragma clang fp contract(off)
    __shared__ float4 pts[2048];      // 32 KB
    __shared__ float  rb[2][256];
    __shared__ int    ri[2][256];

    const int tid = (int)threadIdx.x;
    const int kl  = tid & 255;
    const int s   = tid >> 8;         // 0/1, wave-uniform
    const int b   = blockIdx.y;
    const int k   = blockIdx.x * 256 + kl;

    const float bx = basis[k * 3 + 0];
    const float by = basis[k * 3 + 1];
    const float bz = basis[k * 3 + 2];
    const float nbx = -2.0f * bx, nby = -2.0f * by, nbz = -2.0f * bz;

    float best = 3.4028235e38f;
    int   bi   = 0;

    for (int ph = 0; ph < 2; ++ph) {
        const int base = ph * 2048;
        __syncthreads();   // previous-phase readers done before restage
        for (int t = tid; t < 2048; t += 512) {
            const float* pp = pc + ((size_t)b * N_ + base + t) * 3;
            float x = pp[0], y = pp[1], z = pp[2];
            pts[t] = make_float4(x, y, z, (x * x + y * y) + z * z);
        }
        __syncthreads();
        const int h0 = s * 1024;       // wave-uniform LDS base -> broadcast
#pragma unroll 4
        for (int n = 0; n < 1024; ++n) {
            float4 p = pts[h0 + n];
            float e2 = __builtin_fmaf(nbx, p.x,
                        __builtin_fmaf(nby, p.y,
                         __builtin_fmaf(nbz, p.z, p.w)));
            if (e2 < best) { best = e2; bi = base + h0 + n; }  // strict <
        }
    }

    rb[s][kl] = best;
    ri[s][kl] = bi;
    __syncthreads();

    if (tid < 256) {
        float bb = rb[0][tid]; int ii = ri[0][tid];
        if (rb[1][tid] < bb) { bb = rb[1][tid]; ii = ri[1][tid]; }

        const float* p = pc + ((size_t)b * N_ + ii) * 3;
        const int kk = blockIdx.x * 256 + tid;
        float dx = p[0] - basis[kk * 3 + 0];
        float dy = p[1] - basis[kk * 3 + 1];
        float dz = p[2] - basis[kk * 3 + 2];
        float dist = sqrtf((dx * dx + dy * dy) + dz * dz);

        float* row = bps_out + (size_t)b * IN_;
        row[kk]               = dist;
        row[K_ + 3 * kk + 0]  = dx;
        row[K_ + 3 * kk + 1]  = dy;
        row[K_ + 3 * kk + 2]  = dz;
    }
}

// -------------------------------------------------------------------------
// L1 GEMM: block = 4 waves; wave w -> batches 4w..4w+3 read as 4 scalar
// streams from bps (wave-uniform -> s_load); lane -> 2 columns (float2 W
// load, 512B/wave coalesced). grid (8 colblocks, 64 k-chunks) = 512 blocks.
// partial layout: [chunk][batch(16)][H1]
// -------------------------------------------------------------------------
template<int ILEN, int NCOLS>
__global__ __launch_bounds__(256) void gemm1(
    const float* __restrict__ A, const float* __restrict__ W,
    float* __restrict__ part)
{
    const int lane = (int)threadIdx.x & 63;
    const int wg   = __builtin_amdgcn_readfirstlane((int)threadIdx.x >> 6);
    const int j0   = blockIdx.x * 128 + lane * 2;
    const int i0   = blockIdx.y * ILEN;

    const float* A0 = A + (size_t)(4 * wg + 0) * IN_ + i0;
    const float* A1 = A + (size_t)(4 * wg + 1) * IN_ + i0;
    const float* A2 = A + (size_t)(4 * wg + 2) * IN_ + i0;
    const float* A3 = A + (size_t)(4 * wg + 3) * IN_ + i0;

    float2 acc0 = {0.f, 0.f}, acc1 = {0.f, 0.f}, acc2 = {0.f, 0.f}, acc3 = {0.f, 0.f};

#pragma unroll 8
    for (int i = 0; i < ILEN; ++i) {
        float2 wv = *(const float2*)(W + (size_t)(i0 + i) * NCOLS + j0);
        float a0 = A0[i], a1 = A1[i], a2 = A2[i], a3 = A3[i];
        acc0.x = __builtin_fmaf(a0, wv.x, acc0.x);
        acc0.y = __builtin_fmaf(a0, wv.y, acc0.y);
        acc1.x = __builtin_fmaf(a1, wv.x, acc1.x);
        acc1.y = __builtin_fmaf(a1, wv.y, acc1.y);
        acc2.x = __builtin_fmaf(a2, wv.x, acc2.x);
        acc2.y = __builtin_fmaf(a2, wv.y, acc2.y);
        acc3.x = __builtin_fmaf(a3, wv.x, acc3.x);
        acc3.y = __builtin_fmaf(a3, wv.y, acc3.y);
    }

    float* base = part + (size_t)blockIdx.y * 16 * NCOLS;
    *(float2*)(base + (size_t)(4 * wg + 0) * NCOLS + j0) = acc0;
    *(float2*)(base + (size_t)(4 * wg + 1) * NCOLS + j0) = acc1;
    *(float2*)(base + (size_t)(4 * wg + 2) * NCOLS + j0) = acc2;
    *(float2*)(base + (size_t)(4 * wg + 3) * NCOLS + j0) = acc3;
}

// -------------------------------------------------------------------------
// Reduce 64 chunk-partials + bias + leaky -> h1T[col][16]
// -------------------------------------------------------------------------
__global__ __launch_bounds__(256) void reduce_act1(
    const float* __restrict__ part, const float* __restrict__ bias,
    float* __restrict__ outT)
{
    const int p = blockIdx.x * 256 + (int)threadIdx.x;   // b*H1 + col
    float s = 0.0f;
#pragma unroll 8
    for (int c = 0; c < 64; ++c) s += part[(size_t)c * (16 * H1_) + p];
    const int col = p & (H1_ - 1);
    const int b   = p >> 10;
    s += bias[col];
    s = fmaxf(s, LEAKY_SLOPE * s);
    outT[(size_t)col * 16 + b] = s;
}

// -------------------------------------------------------------------------
// Small fused GEMM (L2/L3): one dispatch, full K. 512 threads = 8 waves;
// wave w -> k-slice; lane -> one column; 16 batch accs; LDS cross-wave
// reduce; bias (+leaky) inline.  AT layout [i][16] -> s_load_dwordx16.
// -------------------------------------------------------------------------
template<int KDIM, int NCOLS>
__global__ __launch_bounds__(512) void gemm_small(
    const float* __restrict__ AT, const float* __restrict__ W,
    const float* __restrict__ bias,
    float* __restrict__ outT, float* __restrict__ out_rm)
{
    __shared__ float red[8][64][17];
    const int lane = (int)threadIdx.x & 63;
    const int w    = __builtin_amdgcn_readfirstlane((int)threadIdx.x >> 6);
    const int j    = blockIdx.x * 64 + lane;
    constexpr int KQ = KDIM / 8;
    const int i0 = w * KQ;

    float acc[16];
#pragma unroll
    for (int r = 0; r < 16; ++r) acc[r] = 0.0f;

#pragma unroll 4
    for (int i = i0; i < i0 + KQ; ++i) {
        float wv = W[(size_t)i * NCOLS + j];
        const float4* Ar = (const float4*)(AT + (size_t)i * 16);
        float4 q0 = Ar[0], q1 = Ar[1], q2 = Ar[2], q3 = Ar[3];
        acc[0]  = __builtin_fmaf(q0.x, wv, acc[0]);
        acc[1]  = __builtin_fmaf(q0.y, wv, acc[1]);
        acc[2]  = __builtin_fmaf(q0.z, wv, acc[2]);
        acc[3]  = __builtin_fmaf(q0.w, wv, acc[3]);
        acc[4]  = __builtin_fmaf(q1.x, wv, acc[4]);
        acc[5]  = __builtin_fmaf(q1.y, wv, acc[5]);
        acc[6]  = __builtin_fmaf(q1.z, wv, acc[6]);
        acc[7]  = __builtin_fmaf(q1.w, wv, acc[7]);
        acc[8]  = __builtin_fmaf(q2.x, wv, acc[8]);
        acc[9]  = __builtin_fmaf(q2.y, wv, acc[9]);
        acc[10] = __builtin_fmaf(q2.z, wv, acc[10]);
        acc[11] = __builtin_fmaf(q2.w, wv, acc[11]);
        acc[12] = __builtin_fmaf(q3.x, wv, acc[12]);
        acc[13] = __builtin_fmaf(q3.y, wv, acc[13]);
        acc[14] = __builtin_fmaf(q3.z, wv, acc[14]);
        acc[15] = __builtin_fmaf(q3.w, wv, acc[15]);
    }

#pragma unroll
    for (int r = 0; r < 16; ++r) red[w][lane][r] = acc[r];
    __syncthreads();

#pragma unroll
    for (int q = 0; q < 2; ++q) {
        int p  = (int)threadIdx.x * 2 + q;   // col_local*16 + batch
        int cl = p >> 4;
        int bt = p & 15;
        float s = bias[blockIdx.x * 64 + cl];
#pragma unroll
        for (int ww = 0; ww < 8; ++ww) s += red[ww][cl][bt];
        if (outT) {
            s = fmaxf(s, LEAKY_SLOPE * s);
            outT[((size_t)blockIdx.x * 64 + cl) * 16 + bt] = s;
        }
        if (out_rm) {
            out_rm[(size_t)bt * NCOLS + blockIdx.x * 64 + cl] = s;
        }
    }
}

// -------------------------------------------------------------------------
extern "C" void kernel_launch(void* const* d_in, const int* in_sizes, int n_in,
                              void* d_out, int out_size, void* d_ws, size_t ws_size,
                              hipStream_t stream)
{
    const float* pc    = (const float*)d_in[0];
    const float* basis = (const float*)d_in[1];
    const float* W1    = (const float*)d_in[2];
    const float* b1    = (const float*)d_in[3];
    const float* W2    = (const float*)d_in[4];
    const float* b2    = (const float*)d_in[5];
    const float* W3    = (const float*)d_in[6];
    const float* b3    = (const float*)d_in[7];

    float* out   = (float*)d_out;
    float* gfeat = out;                 // [16][256]
    float* bps   = out + B_ * OUT_;     // [16][16384]

    char* ws = (char*)d_ws;
    float* partial = (float*)ws;                                 // 4MB
    float* h1T     = (float*)(ws + (size_t)4 * 1024 * 1024);     // 64KB
    float* h2T     = (float*)(ws + (size_t)4 * 1024 * 1024 + 64 * 1024); // 32KB

    // 1) fused BPS encode (no memset, no atomics, no finish pass)
    enc_fused<<<dim3(K_ / 256, B_), 512, 0, stream>>>(pc, basis, bps);
    // 2) L1 GEMM [16,16384]@[16384,1024]; 8 colblocks x 64 chunks
    gemm1<256, H1_><<<dim3(8, 64), 256, 0, stream>>>(bps, W1, partial);
    // 3) reduce + bias + leaky -> h1T
    reduce_act1<<<(H1_ * 16) / 256, 256, 0, stream>>>(partial, b1, h1T);
    // 4) L2 fused [16,1024]@[1024,512]
    gemm_small<1024, H2_><<<8, 512, 0, stream>>>(h1T, W2, b2, h2T, nullptr);
    // 5) L3 fused [16,512]@[512,256] -> final output
    gemm_small<512, OUT_><<<4, 512, 0, stream>>>(h2T, W3, b3, nullptr, gfeat);
}

// Round 6
// 212.000 us; speedup vs baseline: 1.2746x; 1.1138x over previous
//
#include <hip/hip_runtime.h>

#define LEAKY_SLOPE 0.2f

constexpr int B_   = 16;
constexpr int N_   = 4096;
constexpr int K_   = 4096;
constexpr int IN_  = 16384;   // K + 3K
constexpr int H1_  = 1024;
constexpr int H2_  = 512;
constexpr int OUT_ = 256;

// encode tiling: 32 n-chunks x 128 points (2KB LDS), 8 k per thread
constexpr int NCH = 32;
constexpr int NPC = N_ / NCH;   // 128
constexpr int KPT = 8;
constexpr int KTB = 256 * KPT;  // 2048 k per block -> grid.x = 2

// -------------------------------------------------------------------------
// Partial argmin over an n-chunk, folded via u64 atomicMin on
// (orderable_e2_bits << 32 | n).  e2 = pn - 2*cross (bn constant in the
// argmin over n; validated rounds 3-5).  6 VALU ops per (k,n) pair; one
// ds_read_b128 feeds 8 k's.  grid = (2,16,32) = 1024 blocks, 16 waves/CU.
// -------------------------------------------------------------------------
__global__ __launch_bounds__(256) void enc_partial(
    const float* __restrict__ pc, const float* __restrict__ basis,
    unsigned long long* __restrict__ packed)
{
#pragma clang fp contract(off)
    __shared__ float4 pts[NPC];
    const int kt = blockIdx.x;
    const int b  = blockIdx.y;
    const int c  = blockIdx.z;
    const int n0 = c * NPC;

    if (threadIdx.x < NPC) {
        const float* pp = pc + ((size_t)b * N_ + n0 + threadIdx.x) * 3;
        float x = pp[0], y = pp[1], z = pp[2];
        pts[threadIdx.x] = make_float4(x, y, z, (x * x + y * y) + z * z);
    }
    __syncthreads();

    const int k0 = kt * KTB + (int)threadIdx.x;
    float nbx[KPT], nby[KPT], nbz[KPT], best[KPT];
    int   bi[KPT];
#pragma unroll
    for (int q = 0; q < KPT; ++q) {
        int k = k0 + q * 256;
        nbx[q] = -2.0f * basis[k * 3 + 0];
        nby[q] = -2.0f * basis[k * 3 + 1];
        nbz[q] = -2.0f * basis[k * 3 + 2];
        best[q] = 3.4028235e38f;
        bi[q] = 0;
    }

#pragma unroll 2
    for (int n = 0; n < NPC; ++n) {
        float4 p = pts[n];
#pragma unroll
        for (int q = 0; q < KPT; ++q) {
            float e2 = __builtin_fmaf(nbx[q], p.x,
                        __builtin_fmaf(nby[q], p.y,
                         __builtin_fmaf(nbz[q], p.z, p.w)));
            if (e2 < best[q]) { best[q] = e2; bi[q] = n0 + n; }  // strict <
        }
    }

#pragma unroll
    for (int q = 0; q < KPT; ++q) {
        unsigned u = __float_as_uint(best[q]);
        u = (u & 0x80000000u) ? ~u : (u | 0x80000000u);   // monotone map
        unsigned long long v = ((unsigned long long)u << 32) | (unsigned)bi[q];
        atomicMin(&packed[(size_t)b * K_ + (k0 + q * 256)], v);
    }
}

// -------------------------------------------------------------------------
// Unpack argmin index, gather nearest point, write bps feature row.
// -------------------------------------------------------------------------
__global__ __launch_bounds__(256) void enc_finish(
    const float* __restrict__ pc, const float* __restrict__ basis,
    const unsigned long long* __restrict__ packed,
    float* __restrict__ bps_out)
{
#pragma clang fp contract(off)
    const int t = blockIdx.x * 256 + (int)threadIdx.x;   // 0 .. B*K-1
    const int b = t >> 12;
    const int k = t & (K_ - 1);

    const int bi = (int)(unsigned)(packed[t] & 0xffffffffull);

    const float* p = pc + ((size_t)b * N_ + bi) * 3;
    float dx = p[0] - basis[k * 3 + 0];
    float dy = p[1] - basis[k * 3 + 1];
    float dz = p[2] - basis[k * 3 + 2];
    float dist = sqrtf((dx * dx + dy * dy) + dz * dz);

    float* row = bps_out + (size_t)b * IN_;
    row[k]              = dist;
    row[K_ + 3 * k + 0] = dx;
    row[K_ + 3 * k + 1] = dy;
    row[K_ + 3 * k + 2] = dz;
}

// -------------------------------------------------------------------------
// L1 GEMM: 4 waves/block; wave w -> batches 4w..4w+3 as 4 scalar streams
// from bps rows (wave-uniform -> s_load); lane -> 2 cols (float2 W load,
// 512B/wave coalesced).  grid (8 colblocks, 64 k-chunks) = 512 blocks.
// partial: [chunk][batch(16)][H1]
// -------------------------------------------------------------------------
template<int ILEN, int NCOLS>
__global__ __launch_bounds__(256) void gemm1(
    const float* __restrict__ A, const float* __restrict__ W,
    float* __restrict__ part)
{
    const int lane = (int)threadIdx.x & 63;
    const int wg   = __builtin_amdgcn_readfirstlane((int)threadIdx.x >> 6);
    const int j0   = blockIdx.x * 128 + lane * 2;
    const int i0   = blockIdx.y * ILEN;

    const float* A0 = A + (size_t)(4 * wg + 0) * IN_ + i0;
    const float* A1 = A + (size_t)(4 * wg + 1) * IN_ + i0;
    const float* A2 = A + (size_t)(4 * wg + 2) * IN_ + i0;
    const float* A3 = A + (size_t)(4 * wg + 3) * IN_ + i0;

    float2 acc0 = {0.f, 0.f}, acc1 = {0.f, 0.f}, acc2 = {0.f, 0.f}, acc3 = {0.f, 0.f};

#pragma unroll 8
    for (int i = 0; i < ILEN; ++i) {
        float2 wv = *(const float2*)(W + (size_t)(i0 + i) * NCOLS + j0);
        float a0 = A0[i], a1 = A1[i], a2 = A2[i], a3 = A3[i];
        acc0.x = __builtin_fmaf(a0, wv.x, acc0.x);
        acc0.y = __builtin_fmaf(a0, wv.y, acc0.y);
        acc1.x = __builtin_fmaf(a1, wv.x, acc1.x);
        acc1.y = __builtin_fmaf(a1, wv.y, acc1.y);
        acc2.x = __builtin_fmaf(a2, wv.x, acc2.x);
        acc2.y = __builtin_fmaf(a2, wv.y, acc2.y);
        acc3.x = __builtin_fmaf(a3, wv.x, acc3.x);
        acc3.y = __builtin_fmaf(a3, wv.y, acc3.y);
    }

    float* base = part + (size_t)blockIdx.y * 16 * NCOLS;
    *(float2*)(base + (size_t)(4 * wg + 0) * NCOLS + j0) = acc0;
    *(float2*)(base + (size_t)(4 * wg + 1) * NCOLS + j0) = acc1;
    *(float2*)(base + (size_t)(4 * wg + 2) * NCOLS + j0) = acc2;
    *(float2*)(base + (size_t)(4 * wg + 3) * NCOLS + j0) = acc3;
}

// -------------------------------------------------------------------------
// Reduce 64 chunk-partials + bias + leaky -> h1T[col][16]
// -------------------------------------------------------------------------
__global__ __launch_bounds__(256) void reduce_act1(
    const float* __restrict__ part, const float* __restrict__ bias,
    float* __restrict__ outT)
{
    const int p = blockIdx.x * 256 + (int)threadIdx.x;   // b*H1 + col
    float s = 0.0f;
#pragma unroll 8
    for (int c = 0; c < 64; ++c) s += part[(size_t)c * (16 * H1_) + p];
    const int col = p & (H1_ - 1);
    const int b   = p >> 10;
    s += bias[col];
    s = fmaxf(s, LEAKY_SLOPE * s);
    outT[(size_t)col * 16 + b] = s;
}

// -------------------------------------------------------------------------
// Small fused GEMM (L2/L3): one dispatch, full K. 512 threads = 8 waves;
// wave w -> k-slice; lane -> one column; 16 batch accs; LDS cross-wave
// reduce; bias (+leaky) inline.  AT layout [i][16].
// -------------------------------------------------------------------------
template<int KDIM, int NCOLS>
__global__ __launch_bounds__(512) void gemm_small(
    const float* __restrict__ AT, const float* __restrict__ W,
    const float* __restrict__ bias,
    float* __restrict__ outT, float* __restrict__ out_rm)
{
    __shared__ float red[8][64][17];
    const int lane = (int)threadIdx.x & 63;
    const int w    = __builtin_amdgcn_readfirstlane((int)threadIdx.x >> 6);
    const int j    = blockIdx.x * 64 + lane;
    constexpr int KQ = KDIM / 8;
    const int i0 = w * KQ;

    float acc[16];
#pragma unroll
    for (int r = 0; r < 16; ++r) acc[r] = 0.0f;

#pragma unroll 4
    for (int i = i0; i < i0 + KQ; ++i) {
        float wv = W[(size_t)i * NCOLS + j];
        const float4* Ar = (const float4*)(AT + (size_t)i * 16);
        float4 q0 = Ar[0], q1 = Ar[1], q2 = Ar[2], q3 = Ar[3];
        acc[0]  = __builtin_fmaf(q0.x, wv, acc[0]);
        acc[1]  = __builtin_fmaf(q0.y, wv, acc[1]);
        acc[2]  = __builtin_fmaf(q0.z, wv, acc[2]);
        acc[3]  = __builtin_fmaf(q0.w, wv, acc[3]);
        acc[4]  = __builtin_fmaf(q1.x, wv, acc[4]);
        acc[5]  = __builtin_fmaf(q1.y, wv, acc[5]);
        acc[6]  = __builtin_fmaf(q1.z, wv, acc[6]);
        acc[7]  = __builtin_fmaf(q1.w, wv, acc[7]);
        acc[8]  = __builtin_fmaf(q2.x, wv, acc[8]);
        acc[9]  = __builtin_fmaf(q2.y, wv, acc[9]);
        acc[10] = __builtin_fmaf(q2.z, wv, acc[10]);
        acc[11] = __builtin_fmaf(q2.w, wv, acc[11]);
        acc[12] = __builtin_fmaf(q3.x, wv, acc[12]);
        acc[13] = __builtin_fmaf(q3.y, wv, acc[13]);
        acc[14] = __builtin_fmaf(q3.z, wv, acc[14]);
        acc[15] = __builtin_fmaf(q3.w, wv, acc[15]);
    }

#pragma unroll
    for (int r = 0; r < 16; ++r) red[w][lane][r] = acc[r];
    __syncthreads();

#pragma unroll
    for (int q = 0; q < 2; ++q) {
        int p  = (int)threadIdx.x * 2 + q;   // col_local*16 + batch
        int cl = p >> 4;
        int bt = p & 15;
        float s = bias[blockIdx.x * 64 + cl];
#pragma unroll
        for (int ww = 0; ww < 8; ++ww) s += red[ww][cl][bt];
        if (outT) {
            s = fmaxf(s, LEAKY_SLOPE * s);
            outT[((size_t)blockIdx.x * 64 + cl) * 16 + bt] = s;
        }
        if (out_rm) {
            out_rm[(size_t)bt * NCOLS + blockIdx.x * 64 + cl] = s;
        }
    }
}

// -------------------------------------------------------------------------
extern "C" void kernel_launch(void* const* d_in, const int* in_sizes, int n_in,
                              void* d_out, int out_size, void* d_ws, size_t ws_size,
                              hipStream_t stream)
{
    const float* pc    = (const float*)d_in[0];
    const float* basis = (const float*)d_in[1];
    const float* W1    = (const float*)d_in[2];
    const float* b1    = (const float*)d_in[3];
    const float* W2    = (const float*)d_in[4];
    const float* b2    = (const float*)d_in[5];
    const float* W3    = (const float*)d_in[6];
    const float* b3    = (const float*)d_in[7];

    float* out   = (float*)d_out;
    float* gfeat = out;                 // [16][256]
    float* bps   = out + B_ * OUT_;     // [16][16384]

    char* ws = (char*)d_ws;
    unsigned long long* packed = (unsigned long long*)ws;        // 512KB
    float* partial = (float*)(ws + (size_t)1024 * 1024);         // 4MB
    float* h1T     = (float*)(ws + (size_t)5 * 1024 * 1024);     // 64KB
    float* h2T     = (float*)(ws + (size_t)5 * 1024 * 1024 + 64 * 1024); // 32KB

    // 1) init packed keys to +inf
    hipMemsetAsync(packed, 0xFF, (size_t)B_ * K_ * 8, stream);
    // 2) partial argmin, atomic fold (1024 blocks, 16 waves/CU)
    enc_partial<<<dim3(K_ / KTB, B_, NCH), 256, 0, stream>>>(pc, basis, packed);
    // 3) gather + write bps feature
    enc_finish<<<(B_ * K_) / 256, 256, 0, stream>>>(pc, basis, packed, bps);
    // 4) L1 GEMM [16,16384]@[16384,1024]; 8 colblocks x 64 chunks
    gemm1<256, H1_><<<dim3(8, 64), 256, 0, stream>>>(bps, W1, partial);
    // 5) reduce + bias + leaky -> h1T
    reduce_act1<<<(H1_ * 16) / 256, 256, 0, stream>>>(partial, b1, h1T);
    // 6) L2 fused [16,1024]@[1024,512]
    gemm_small<1024, H2_><<<8, 512, 0, stream>>>(h1T, W2, b2, h2T, nullptr);
    // 7) L3 fused [16,512]@[512,256] -> final output
    gemm_small<512, OUT_><<<4, 512, 0, stream>>>(h2T, W3, b3, nullptr, gfeat);
}